// Round 2
// baseline (244.080 us; speedup 1.0000x reference)
//
#include <hip/hip_runtime.h>

// hardwiredAttention: out[b,i,h] = sum_j w[b,i,j] * h_t[j,b,h]
//   w = m_i*m_j*relu(domain[cog,r]-d) / max(w)
// R7 = R6 with the staging stream moved OFF the global_load_lds DMA path.
// Theory: lds-DMA ingestion is latency*outstanding-capped per CU (~5 B/cyc
// observed; m97 gets 23 B/cyc through the same path from L2-resident data),
// which explains R3-R6's depth-insensitive, rotation-insensitive, linear-in-
// bytes pin at ~3.2 TB/s aggregate. Producers now do nontemporal b128 loads
// into a 2-deep VGPR ping-pong and ds_write_b128 with the XOR swizzle applied
// on the WRITE address (LDS image identical -> consumer code unchanged).
// LDS pipeline depth now lives in VGPRs, so tiles shrink 4->2 bufs
// (121 KB -> 72 KB) => 2 blocks/CU: all 512 blocks co-resident, no tail.
// (R7b: use ext_vector_type for nontemporal_load — HIP uint4 is a struct
// and the builtin rejects it.)

#define B_   64
#define N_   512
#define H_   128
#define NCOG 72
#define NRB  72

typedef __bf16 bf16x8 __attribute__((ext_vector_type(8)));
typedef float  f32x4  __attribute__((ext_vector_type(4)));
typedef unsigned int u32x4 __attribute__((ext_vector_type(4)));

// ---------- h_t[j][b][h] fp32 -> T[b][h][j] bf16 ----------
__global__ __launch_bounds__(256) void k_transpose(const float* __restrict__ ht,
                                                   __bf16* __restrict__ T) {
    __shared__ __bf16 tile[32][136];
    const int jt = blockIdx.x * 32;
    const int b  = blockIdx.y;
    const int t  = threadIdx.x;
    {
        const int jj = t >> 3;
        const int h0 = (t & 7) << 4;
        const float* src = ht + ((size_t)(jt + jj) * B_ + b) * H_ + h0;
        float4 v0 = *(const float4*)(src + 0);
        float4 v1 = *(const float4*)(src + 4);
        float4 v2 = *(const float4*)(src + 8);
        float4 v3 = *(const float4*)(src + 12);
        __bf16* dst = &tile[jj][h0];
        dst[0]=(__bf16)v0.x; dst[1]=(__bf16)v0.y; dst[2]=(__bf16)v0.z; dst[3]=(__bf16)v0.w;
        dst[4]=(__bf16)v1.x; dst[5]=(__bf16)v1.y; dst[6]=(__bf16)v1.z; dst[7]=(__bf16)v1.w;
        dst[8]=(__bf16)v2.x; dst[9]=(__bf16)v2.y; dst[10]=(__bf16)v2.z; dst[11]=(__bf16)v2.w;
        dst[12]=(__bf16)v3.x; dst[13]=(__bf16)v3.y; dst[14]=(__bf16)v3.z; dst[15]=(__bf16)v3.w;
    }
    __syncthreads();
    {
        const int h  = t >> 1;
        const int j0 = (t & 1) << 4;
        union { bf16x8 v[2]; __bf16 e[16]; } ob;
        #pragma unroll
        for (int q = 0; q < 16; ++q) ob.e[q] = tile[j0 + q][h];
        __bf16* dst = T + ((size_t)b * H_ + h) * N_ + jt + j0;
        *(bf16x8*)(dst + 0) = ob.v[0];
        *(bf16x8*)(dst + 8) = ob.v[1];
    }
}

// ---------- producer/consumer fused kernel, reg-staged pipeline ----------
__global__ __launch_bounds__(512, 4) void k_main(const int* __restrict__ cog,
                                                 const int* __restrict__ rmat,
                                                 const float* __restrict__ dmat,
                                                 const float* __restrict__ mask,
                                                 const float* __restrict__ domain,
                                                 const __bf16* __restrict__ T,
                                                 float* __restrict__ out,
                                                 unsigned int* __restrict__ gmax) {
    __shared__ int   tiles[2 * 3 * 2048];   // [buf][array][64 rows x 32 k] 48 KB
    __shared__ float sdom[NCOG * NRB];      // 20736 B
    __shared__ float smask[N_];             // 2048 B
    __shared__ float swmax[8];

    // XCD swizzle: same-b blocks land on the same XCD (ids differ by 8)
    const int id    = blockIdx.x;
    const int xcd   = id & 7;
    const int i0idx = (id >> 3) & 7;
    const int bhi   = id >> 6;
    const int b     = xcd + 8 * bhi;
    const int i0    = i0idx * 64;
    const int kstart = (id & 15) * 32;      // K-phase rotation (kept from R6)

    const int t    = threadIdx.x;
    const int wave = t >> 6;
    const int lane = t & 63;

    for (int k = t; k < NCOG * NRB; k += 512) sdom[k] = domain[k];
    for (int k = t; k < N_; k += 512) smask[k] = mask[b * N_ + k];

    const size_t robase = ((size_t)b * N_ + i0) * N_;   // element offset of tile row 0

    float wmax = 0.0f;

    if (wave >= 4) {
        // ================= producer (reg-staging) =================
        const int pw = wave - 4;                 // 0..3
        const int r  = lane >> 3;                // row within octet (0..7)
        const int c  = lane & 7;                 // 16B chunk within row (0..7)
        const size_t gl_off = (size_t)r * N_ + c * 4;      // contiguous global read
        const int    ds_off = r * 32 + ((c ^ r) << 2);     // XOR-swizzled LDS write (ints)

        u32x4 regs[2][6];

        // batch n -> regset n&1; LDS buf n&1. 6 b128 loads/wave/batch.
        #define LOAD_BATCH(n, set)                                                   \
            do {                                                                     \
                const int kk_ = (kstart + (n) * 32) & (N_ - 1);                      \
                _Pragma("unroll")                                                    \
                for (int q6 = 0; q6 < 6; ++q6) {                                     \
                    const int q = pw * 6 + q6, a = q >> 3, c8 = q & 7;               \
                    const size_t goff = robase + (size_t)(c8 * 8) * N_ + kk_ + gl_off;\
                    const unsigned int* g = (a == 0) ? (const unsigned int*)cog      \
                                           : (a == 1) ? (const unsigned int*)rmat    \
                                                      : (const unsigned int*)dmat;   \
                    regs[set][q6] = __builtin_nontemporal_load((const u32x4*)(g + goff)); \
                }                                                                    \
            } while (0)

        #define STORE_BATCH(n, set)                                                  \
            do {                                                                     \
                const int buf_ = (n) & 1;                                            \
                _Pragma("unroll")                                                    \
                for (int q6 = 0; q6 < 6; ++q6) {                                     \
                    const int q = pw * 6 + q6, a = q >> 3, c8 = q & 7;               \
                    *(u32x4*)&tiles[buf_ * 6144 + a * 2048 + c8 * 256 + ds_off] = regs[set][q6]; \
                }                                                                    \
            } while (0)

        // prologue: batches 0,1 in flight; publish sdom/smask + batch 0
        LOAD_BATCH(0, 0);
        LOAD_BATCH(1, 1);
        STORE_BATCH(0, 0);   // compiler emits s_waitcnt vmcnt(6) before first use
        asm volatile("s_waitcnt lgkmcnt(0)\n\ts_barrier" ::: "memory");

        #pragma unroll
        for (int s = 0; s < 16; ++s) {
            if (s < 14) LOAD_BATCH(s + 2, s & 1);        // batch s stored last iter
            __builtin_amdgcn_sched_barrier(0);           // keep loads above stores
            if (s < 15) STORE_BATCH(s + 1, (s + 1) & 1); // auto vmcnt(6) / vmcnt(0)
            // NO vmcnt at the barrier: batch s+2 stays in flight across it
            asm volatile("s_waitcnt lgkmcnt(0)\n\ts_barrier" ::: "memory");
        }
        #undef LOAD_BATCH
        #undef STORE_BATCH
    } else {
        // ================= consumer (unchanged except 2-deep buffer) =================
        const int quad = lane >> 4;
        const int lrow = lane & 15;
        const int row  = wave * 16 + lrow;                       // 0..63 local
        const int g0   = (row * 8 + ((quad * 2)     ^ (row & 7))) * 4;
        const int g1   = (row * 8 + ((quad * 2 + 1) ^ (row & 7))) * 4;
        const __bf16* Tcol = T + (size_t)b * H_ * N_ + (size_t)lrow * N_ + quad * 8;

        f32x4 acc[8];
        #pragma unroll
        for (int i = 0; i < 8; ++i) acc[i] = (f32x4)0.0f;

        // preload step-0 T fragments before the first barrier
        bf16x8 bfbuf[2][8];
        #pragma unroll
        for (int nt = 0; nt < 8; ++nt)
            bfbuf[0][nt] = *(const bf16x8*)(Tcol + (size_t)nt * 16 * N_ + kstart);

        __syncthreads();
        #pragma unroll 4
        for (int s = 0; s < 16; ++s) {
            const int kk  = (kstart + s * 32) & (N_ - 1);
            const int cb  = s & 1;
            // prefetch next step's T fragments first (own vmcnt, retired at barrier)
            if (s + 1 < 16) {
                const int kk2 = (kstart + s * 32 + 32) & (N_ - 1);
                #pragma unroll
                for (int nt = 0; nt < 8; ++nt)
                    bfbuf[cb ^ 1][nt] = *(const bf16x8*)(Tcol + (size_t)nt * 16 * N_ + kk2);
            }
            // staged tile (lgkm stream, XOR-swizzled)
            const int jb = kk + quad * 8;
            const int* tb = tiles + (s & 1) * 6144;
            union { int4 v[2]; int   e[8]; } ci, ri;
            union { int4 v[2]; float e[8]; } di;
            ci.v[0] = *(const int4*)(tb + g0);        ci.v[1] = *(const int4*)(tb + g1);
            ri.v[0] = *(const int4*)(tb + 2048 + g0); ri.v[1] = *(const int4*)(tb + 2048 + g1);
            di.v[0] = *(const int4*)(tb + 4096 + g0); di.v[1] = *(const int4*)(tb + 4096 + g1);

            union { bf16x8 v8; __bf16 e[8]; } af;
            #pragma unroll
            for (int q = 0; q < 8; ++q) {
                float val = sdom[ci.e[q] * NRB + ri.e[q]] - di.e[q];
                val = fmaxf(val, 0.0f) * smask[jb + q];
                wmax = fmaxf(wmax, val);
                af.e[q] = (__bf16)val;
            }
            #pragma unroll
            for (int nt = 0; nt < 8; ++nt)
                acc[nt] = __builtin_amdgcn_mfma_f32_16x16x32_bf16(af.v8, bfbuf[cb][nt], acc[nt], 0, 0, 0);
            __syncthreads();
        }

        wmax *= smask[i0 + row];   // fold mask_i (lane's elements are all row `row`)

        // unnormalized output; D layout: col=lane&15, row=quad*4+reg
        const int orow0 = i0 + wave * 16 + quad * 4;
        #pragma unroll
        for (int nt = 0; nt < 8; ++nt) {
            #pragma unroll
            for (int r = 0; r < 4; ++r)
                out[((size_t)b * N_ + orow0 + r) * H_ + nt * 16 + lrow] = acc[nt][r];
        }
    }

    // block max -> one atomic
    #pragma unroll
    for (int off = 32; off > 0; off >>= 1)
        wmax = fmaxf(wmax, __shfl_down(wmax, off));
    if (lane == 0) swmax[wave] = wmax;
    __syncthreads();
    if (t == 0) {
        float m = swmax[0];
        #pragma unroll
        for (int w = 1; w < 8; ++w) m = fmaxf(m, swmax[w]);
        atomicMax(gmax, __float_as_uint(m));   // floats >= 0: uint cmp == float cmp
    }
}

// ---------- scale by m_i / gmax ----------
__global__ __launch_bounds__(256) void k_scale(float* __restrict__ out,
                                               const float* __restrict__ mask,
                                               const unsigned int* __restrict__ gmax) {
    const float inv = 1.0f / __uint_as_float(*gmax);
    const int idx = blockIdx.x * 256 + threadIdx.x;     // 1,048,576 float4s
    const float m = mask[idx >> 5] * inv;               // 32 float4 per (b,i) row
    float4* p = (float4*)out;
    float4 v = p[idx];
    v.x *= m; v.y *= m; v.z *= m; v.w *= m;
    p[idx] = v;
}

extern "C" void kernel_launch(void* const* d_in, const int* in_sizes, int n_in,
                              void* d_out, int out_size, void* d_ws, size_t ws_size,
                              hipStream_t stream) {
    const float* ht     = (const float*)d_in[0];   // (N,B,H) f32
    const int*   rmat   = (const int*)  d_in[1];   // (B,N,N) i32
    const float* dmat   = (const float*)d_in[2];   // (B,N,N) f32
    const float* mask   = (const float*)d_in[3];   // (B,N)   f32
    const int*   cog    = (const int*)  d_in[4];   // (B,N,N) i32
    const float* domain = (const float*)d_in[5];   // (72,72) f32
    float* out = (float*)d_out;

    unsigned int* gmax = (unsigned int*)d_ws;
    __bf16* T = (__bf16*)((char*)d_ws + 256);      // 8 MiB bf16 transpose buffer

    hipMemsetAsync(d_ws, 0, 256, stream);          // gmax = 0.0f
    k_transpose<<<dim3(16, 64), 256, 0, stream>>>(ht, T);
    k_main<<<dim3(512), 512, 0, stream>>>(cog, rmat, dmat, mask, domain, T, out, gmax);
    k_scale<<<4096, 256, 0, stream>>>(out, mask, gmax);
}

// Round 3
// 227.113 us; speedup vs baseline: 1.0747x; 1.0747x over previous
//
#include <hip/hip_runtime.h>

// hardwiredAttention: out[b,i,h] = sum_j w[b,i,j] * h_t[j,b,h]
//   w = m_i*m_j*relu(domain[cog,r]-d) / max(w)
// R8 = R7 de-spilled. R7's launch_bounds(512,4) clamped VGPR to 64 ->
// consumer inner loop spilled to scratch (WRITE_SIZE 16.4->69.4 MB smoking
// gun). Fix: unclamped launch_bounds(512) + single-buffered T fragments
// (bfbuf[8], -32 VGPR) to land the consumer under the 128-VGPR / 2-blocks-
// per-CU boundary. T loads issue at step top so L2-hit latency overlaps the
// ds_read+gather chain. Clean test of the "LDS-DMA ingestion is latency*
// outstanding capped" theory: reg-staged loads should beat 4.7 B/cyc/CU.

#define B_   64
#define N_   512
#define H_   128
#define NCOG 72
#define NRB  72

typedef __bf16 bf16x8 __attribute__((ext_vector_type(8)));
typedef float  f32x4  __attribute__((ext_vector_type(4)));
typedef unsigned int u32x4 __attribute__((ext_vector_type(4)));

// ---------- h_t[j][b][h] fp32 -> T[b][h][j] bf16 ----------
__global__ __launch_bounds__(256) void k_transpose(const float* __restrict__ ht,
                                                   __bf16* __restrict__ T) {
    __shared__ __bf16 tile[32][136];
    const int jt = blockIdx.x * 32;
    const int b  = blockIdx.y;
    const int t  = threadIdx.x;
    {
        const int jj = t >> 3;
        const int h0 = (t & 7) << 4;
        const float* src = ht + ((size_t)(jt + jj) * B_ + b) * H_ + h0;
        float4 v0 = *(const float4*)(src + 0);
        float4 v1 = *(const float4*)(src + 4);
        float4 v2 = *(const float4*)(src + 8);
        float4 v3 = *(const float4*)(src + 12);
        __bf16* dst = &tile[jj][h0];
        dst[0]=(__bf16)v0.x; dst[1]=(__bf16)v0.y; dst[2]=(__bf16)v0.z; dst[3]=(__bf16)v0.w;
        dst[4]=(__bf16)v1.x; dst[5]=(__bf16)v1.y; dst[6]=(__bf16)v1.z; dst[7]=(__bf16)v1.w;
        dst[8]=(__bf16)v2.x; dst[9]=(__bf16)v2.y; dst[10]=(__bf16)v2.z; dst[11]=(__bf16)v2.w;
        dst[12]=(__bf16)v3.x; dst[13]=(__bf16)v3.y; dst[14]=(__bf16)v3.z; dst[15]=(__bf16)v3.w;
    }
    __syncthreads();
    {
        const int h  = t >> 1;
        const int j0 = (t & 1) << 4;
        union { bf16x8 v[2]; __bf16 e[16]; } ob;
        #pragma unroll
        for (int q = 0; q < 16; ++q) ob.e[q] = tile[j0 + q][h];
        __bf16* dst = T + ((size_t)b * H_ + h) * N_ + jt + j0;
        *(bf16x8*)(dst + 0) = ob.v[0];
        *(bf16x8*)(dst + 8) = ob.v[1];
    }
}

// ---------- producer/consumer fused kernel, reg-staged pipeline ----------
__global__ __launch_bounds__(512) void k_main(const int* __restrict__ cog,
                                              const int* __restrict__ rmat,
                                              const float* __restrict__ dmat,
                                              const float* __restrict__ mask,
                                              const float* __restrict__ domain,
                                              const __bf16* __restrict__ T,
                                              float* __restrict__ out,
                                              unsigned int* __restrict__ gmax) {
    __shared__ int   tiles[2 * 3 * 2048];   // [buf][array][64 rows x 32 k] 48 KB
    __shared__ float sdom[NCOG * NRB];      // 20736 B
    __shared__ float smask[N_];             // 2048 B
    __shared__ float swmax[8];

    // XCD swizzle: same-b blocks land on the same XCD (ids differ by 8)
    const int id    = blockIdx.x;
    const int xcd   = id & 7;
    const int i0idx = (id >> 3) & 7;
    const int bhi   = id >> 6;
    const int b     = xcd + 8 * bhi;
    const int i0    = i0idx * 64;
    const int kstart = (id & 15) * 32;      // K-phase rotation (kept from R6)

    const int t    = threadIdx.x;
    const int wave = t >> 6;
    const int lane = t & 63;

    for (int k = t; k < NCOG * NRB; k += 512) sdom[k] = domain[k];
    for (int k = t; k < N_; k += 512) smask[k] = mask[b * N_ + k];

    const size_t robase = ((size_t)b * N_ + i0) * N_;   // element offset of tile row 0

    float wmax = 0.0f;

    if (wave >= 4) {
        // ================= producer (reg-staging) =================
        const int pw = wave - 4;                 // 0..3
        const int r  = lane >> 3;                // row within octet (0..7)
        const int c  = lane & 7;                 // 16B chunk within row (0..7)
        const size_t gl_off = (size_t)r * N_ + c * 4;      // contiguous global read
        const int    ds_off = r * 32 + ((c ^ r) << 2);     // XOR-swizzled LDS write (ints)

        u32x4 regs[2][6];

        // batch n -> regset n&1; LDS buf n&1. 6 b128 loads/wave/batch.
        #define LOAD_BATCH(n, set)                                                   \
            do {                                                                     \
                const int kk_ = (kstart + (n) * 32) & (N_ - 1);                      \
                _Pragma("unroll")                                                    \
                for (int q6 = 0; q6 < 6; ++q6) {                                     \
                    const int q = pw * 6 + q6, a = q >> 3, c8 = q & 7;               \
                    const size_t goff = robase + (size_t)(c8 * 8) * N_ + kk_ + gl_off;\
                    const unsigned int* g = (a == 0) ? (const unsigned int*)cog      \
                                           : (a == 1) ? (const unsigned int*)rmat    \
                                                      : (const unsigned int*)dmat;   \
                    regs[set][q6] = __builtin_nontemporal_load((const u32x4*)(g + goff)); \
                }                                                                    \
            } while (0)

        #define STORE_BATCH(n, set)                                                  \
            do {                                                                     \
                const int buf_ = (n) & 1;                                            \
                _Pragma("unroll")                                                    \
                for (int q6 = 0; q6 < 6; ++q6) {                                     \
                    const int q = pw * 6 + q6, a = q >> 3, c8 = q & 7;               \
                    *(u32x4*)&tiles[buf_ * 6144 + a * 2048 + c8 * 256 + ds_off] = regs[set][q6]; \
                }                                                                    \
            } while (0)

        // prologue: batches 0,1 in flight; publish sdom/smask + batch 0
        LOAD_BATCH(0, 0);
        LOAD_BATCH(1, 1);
        STORE_BATCH(0, 0);   // compiler emits s_waitcnt vmcnt(6) before first use
        asm volatile("s_waitcnt lgkmcnt(0)\n\ts_barrier" ::: "memory");

        #pragma unroll
        for (int s = 0; s < 16; ++s) {
            if (s < 14) LOAD_BATCH(s + 2, s & 1);        // batch s stored last iter
            __builtin_amdgcn_sched_barrier(0);           // keep loads above stores
            if (s < 15) STORE_BATCH(s + 1, (s + 1) & 1); // auto vmcnt(6) / vmcnt(0)
            // NO vmcnt at the barrier: batch s+2 stays in flight across it
            asm volatile("s_waitcnt lgkmcnt(0)\n\ts_barrier" ::: "memory");
        }
        #undef LOAD_BATCH
        #undef STORE_BATCH
    } else {
        // ================= consumer (single-buffered T fragments) =================
        const int quad = lane >> 4;
        const int lrow = lane & 15;
        const int row  = wave * 16 + lrow;                       // 0..63 local
        const int g0   = (row * 8 + ((quad * 2)     ^ (row & 7))) * 4;
        const int g1   = (row * 8 + ((quad * 2 + 1) ^ (row & 7))) * 4;
        const __bf16* Tcol = T + (size_t)b * H_ * N_ + (size_t)lrow * N_ + quad * 8;

        f32x4 acc[8];
        #pragma unroll
        for (int i = 0; i < 8; ++i) acc[i] = (f32x4)0.0f;

        __syncthreads();
        #pragma unroll 4
        for (int s = 0; s < 16; ++s) {
            const int kk  = (kstart + s * 32) & (N_ - 1);
            // issue this step's T loads first: L2-hit latency overlaps the
            // ds_read + gather/VALU chain below (vmcnt wait sits before MFMA)
            bf16x8 bfbuf[8];
            #pragma unroll
            for (int nt = 0; nt < 8; ++nt)
                bfbuf[nt] = *(const bf16x8*)(Tcol + (size_t)nt * 16 * N_ + kk);
            // staged tile (lgkm stream, XOR-swizzled)
            const int jb = kk + quad * 8;
            const int* tb = tiles + (s & 1) * 6144;
            union { int4 v[2]; int   e[8]; } ci, ri;
            union { int4 v[2]; float e[8]; } di;
            ci.v[0] = *(const int4*)(tb + g0);        ci.v[1] = *(const int4*)(tb + g1);
            ri.v[0] = *(const int4*)(tb + 2048 + g0); ri.v[1] = *(const int4*)(tb + 2048 + g1);
            di.v[0] = *(const int4*)(tb + 4096 + g0); di.v[1] = *(const int4*)(tb + 4096 + g1);

            union { bf16x8 v8; __bf16 e[8]; } af;
            #pragma unroll
            for (int q = 0; q < 8; ++q) {
                float val = sdom[ci.e[q] * NRB + ri.e[q]] - di.e[q];
                val = fmaxf(val, 0.0f) * smask[jb + q];
                wmax = fmaxf(wmax, val);
                af.e[q] = (__bf16)val;
            }
            #pragma unroll
            for (int nt = 0; nt < 8; ++nt)
                acc[nt] = __builtin_amdgcn_mfma_f32_16x16x32_bf16(af.v8, bfbuf[nt], acc[nt], 0, 0, 0);
            __syncthreads();
        }

        wmax *= smask[i0 + row];   // fold mask_i (lane's elements are all row `row`)

        // unnormalized output; D layout: col=lane&15, row=quad*4+reg
        const int orow0 = i0 + wave * 16 + quad * 4;
        #pragma unroll
        for (int nt = 0; nt < 8; ++nt) {
            #pragma unroll
            for (int r = 0; r < 4; ++r)
                out[((size_t)b * N_ + orow0 + r) * H_ + nt * 16 + lrow] = acc[nt][r];
        }
    }

    // block max -> one atomic
    #pragma unroll
    for (int off = 32; off > 0; off >>= 1)
        wmax = fmaxf(wmax, __shfl_down(wmax, off));
    if (lane == 0) swmax[wave] = wmax;
    __syncthreads();
    if (t == 0) {
        float m = swmax[0];
        #pragma unroll
        for (int w = 1; w < 8; ++w) m = fmaxf(m, swmax[w]);
        atomicMax(gmax, __float_as_uint(m));   // floats >= 0: uint cmp == float cmp
    }
}

// ---------- scale by m_i / gmax ----------
__global__ __launch_bounds__(256) void k_scale(float* __restrict__ out,
                                               const float* __restrict__ mask,
                                               const unsigned int* __restrict__ gmax) {
    const float inv = 1.0f / __uint_as_float(*gmax);
    const int idx = blockIdx.x * 256 + threadIdx.x;     // 1,048,576 float4s
    const float m = mask[idx >> 5] * inv;               // 32 float4 per (b,i) row
    float4* p = (float4*)out;
    float4 v = p[idx];
    v.x *= m; v.y *= m; v.z *= m; v.w *= m;
    p[idx] = v;
}

extern "C" void kernel_launch(void* const* d_in, const int* in_sizes, int n_in,
                              void* d_out, int out_size, void* d_ws, size_t ws_size,
                              hipStream_t stream) {
    const float* ht     = (const float*)d_in[0];   // (N,B,H) f32
    const int*   rmat   = (const int*)  d_in[1];   // (B,N,N) i32
    const float* dmat   = (const float*)d_in[2];   // (B,N,N) f32
    const float* mask   = (const float*)d_in[3];   // (B,N)   f32
    const int*   cog    = (const int*)  d_in[4];   // (B,N,N) i32
    const float* domain = (const float*)d_in[5];   // (72,72) f32
    float* out = (float*)d_out;

    unsigned int* gmax = (unsigned int*)d_ws;
    __bf16* T = (__bf16*)((char*)d_ws + 256);      // 8 MiB bf16 transpose buffer

    hipMemsetAsync(d_ws, 0, 256, stream);          // gmax = 0.0f
    k_transpose<<<dim3(16, 64), 256, 0, stream>>>(ht, T);
    k_main<<<dim3(512), 512, 0, stream>>>(cog, rmat, dmat, mask, domain, T, out, gmax);
    k_scale<<<4096, 256, 0, stream>>>(out, mask, gmax);
}